// Round 6
// baseline (4904.005 us; speedup 1.0000x reference)
//
#include <hip/hip_runtime.h>
#include <math.h>

#define V 64
#define TMAX 2048
#define ED 512
#define H 64
#define G3 192
#define BT 64          // t-rows per k_gemm block
#define CK 32          // k_rec LDS chunk (steps)

typedef const __attribute__((address_space(1))) void gvoid;
typedef __attribute__((address_space(3))) void lvoid;
typedef float vf4 __attribute__((ext_vector_type(4)));

// ---------------- K0: zero the persistent hidden state ----------------
__global__ void k_init(float* __restrict__ h) {
    int i = blockIdx.x * blockDim.x + threadIdx.x;
    if (i < V * H) h[i] = 0.f;
}

// ---------------- K1: xg[v, tloc, g] = b_ih[g] + sum_k emb[v,t,k] * W_ih[g,k]
// Block tile 64t x 192g, 256 thr, thread tile 8t x 6g. K chunk 32, register
// double-buffered staging (next chunk's global loads in flight during compute).
// e-reads broadcast (tq uniform per half-wave); w rows gq+32j -> bank-floor.
__global__ __launch_bounds__(256, 2) void k_gemm(
    const float* __restrict__ emb, const int* __restrict__ lengths,
    const float* __restrict__ W_ih, const float* __restrict__ b_ih,
    float* __restrict__ xg, int c, int CT) {
    int v = blockIdx.y;
    int tile0 = blockIdx.x * BT;
    if (c * CT + tile0 >= lengths[v]) return;  // tile never read downstream

    __shared__ __align__(16) float Es[BT][36];
    __shared__ __align__(16) float Ws[G3][36];

    int th = threadIdx.x;
    int tq = th >> 5;     // 0..7  : t-rows tq*8 .. tq*8+7 (uniform per half-wave)
    int gq = th & 31;     // 0..31 : g-rows gq + 32*j
    int srow = th >> 3;   // staging row 0..31
    int spos = th & 7;    // staging float4 slot

    const float* ebase = emb + ((size_t)v * TMAX + c * CT + tile0) * ED;

    float acc[8][6];
#pragma unroll
    for (int i = 0; i < 8; i++)
#pragma unroll
        for (int j = 0; j < 6; j++) acc[i][j] = 0.f;

    // prologue: load kc=0 into staging regs
    float4 se[2], sw[6];
#pragma unroll
    for (int r = 0; r < 2; r++)
        se[r] = *(const float4*)&ebase[(size_t)(r * 32 + srow) * ED + spos * 4];
#pragma unroll
    for (int r = 0; r < 6; r++)
        sw[r] = *(const float4*)&W_ih[(size_t)(r * 32 + srow) * ED + spos * 4];

    for (int kc = 0; kc < ED; kc += 32) {
        // publish staged regs
#pragma unroll
        for (int r = 0; r < 2; r++) *(float4*)&Es[r * 32 + srow][spos * 4] = se[r];
#pragma unroll
        for (int r = 0; r < 6; r++) *(float4*)&Ws[r * 32 + srow][spos * 4] = sw[r];
        __syncthreads();

        // issue next chunk's loads (land during compute)
        if (kc + 32 < ED) {
#pragma unroll
            for (int r = 0; r < 2; r++)
                se[r] = *(const float4*)&ebase[(size_t)(r * 32 + srow) * ED + kc + 32 + spos * 4];
#pragma unroll
            for (int r = 0; r < 6; r++)
                sw[r] = *(const float4*)&W_ih[(size_t)(r * 32 + srow) * ED + kc + 32 + spos * 4];
        }

#pragma unroll
        for (int k4 = 0; k4 < 8; k4++) {
            float4 e[8], w[6];
#pragma unroll
            for (int i = 0; i < 8; i++) e[i] = *(float4*)&Es[tq * 8 + i][k4 * 4];
#pragma unroll
            for (int j = 0; j < 6; j++) w[j] = *(float4*)&Ws[gq + 32 * j][k4 * 4];
#pragma unroll
            for (int i = 0; i < 8; i++)
#pragma unroll
                for (int j = 0; j < 6; j++)
                    acc[i][j] += e[i].x * w[j].x + e[i].y * w[j].y +
                                 e[i].z * w[j].z + e[i].w * w[j].w;
        }
        __syncthreads();
    }

    float bj[6];
#pragma unroll
    for (int j = 0; j < 6; j++) bj[j] = b_ih[gq + 32 * j];

#pragma unroll
    for (int i = 0; i < 8; i++) {
        size_t ob = ((size_t)v * CT + tile0 + tq * 8 + i) * G3 + gq;
#pragma unroll
        for (int j = 0; j < 6; j++)
            xg[ob + 32 * j] = acc[i][j] + bj[j];
    }
}

// ---------------- K2: GRU recurrence, ONE WAVE per var, zero barriers.
// Lane l holds W_hh rows l (r), 64+l (z), 128+l (n) as 48 NAMED vf4s,
// pinned into VGPRs with an asm register-redefinition so the compiler cannot
// sink the loads into the loop (R4 failure mode: VGPR=148 -> cache re-reads).
// xg staged via lane-contiguous global_load_lds, 32-step double buffer.
#define LDW3(i) \
    vf4 wr##i = *(const vf4*)&W_hh[(size_t)l * H + (i) * 4];          \
    vf4 wz##i = *(const vf4*)&W_hh[(size_t)(64 + l) * H + (i) * 4];   \
    vf4 wn##i = *(const vf4*)&W_hh[(size_t)(128 + l) * H + (i) * 4];

#define FMA4(acw, wv, hvv) \
    acw = fmaf((wv).x, (hvv).x, acw); acw = fmaf((wv).y, (hvv).y, acw); \
    acw = fmaf((wv).z, (hvv).z, acw); acw = fmaf((wv).w, (hvv).w, acw);

__global__ __launch_bounds__(64, 1) void k_rec(
    const float* __restrict__ xg, const int* __restrict__ lengths,
    const float* __restrict__ W_hh, const float* __restrict__ b_hh,
    float* __restrict__ h, int c, int CT) {
    int v = blockIdx.x;
    int l = threadIdx.x;
    int rem = lengths[v] - c * CT;
    int tcnt = rem < 0 ? 0 : (rem > CT ? CT : rem);

    __shared__ __align__(16) float hs[H];
    __shared__ __align__(16) float xb[2][CK * G3];   // 2 x 24 KB

    LDW3(0)  LDW3(1)  LDW3(2)  LDW3(3)  LDW3(4)  LDW3(5)  LDW3(6)  LDW3(7)
    LDW3(8)  LDW3(9)  LDW3(10) LDW3(11) LDW3(12) LDW3(13) LDW3(14) LDW3(15)
    // pin: asm redefines each value -> loads cannot be sunk past this point
    asm volatile("" : "+v"(wr0), "+v"(wr1), "+v"(wr2), "+v"(wr3),
                      "+v"(wr4), "+v"(wr5), "+v"(wr6), "+v"(wr7),
                      "+v"(wr8), "+v"(wr9), "+v"(wr10), "+v"(wr11),
                      "+v"(wr12), "+v"(wr13), "+v"(wr14), "+v"(wr15));
    asm volatile("" : "+v"(wz0), "+v"(wz1), "+v"(wz2), "+v"(wz3),
                      "+v"(wz4), "+v"(wz5), "+v"(wz6), "+v"(wz7),
                      "+v"(wz8), "+v"(wz9), "+v"(wz10), "+v"(wz11),
                      "+v"(wz12), "+v"(wz13), "+v"(wz14), "+v"(wz15));
    asm volatile("" : "+v"(wn0), "+v"(wn1), "+v"(wn2), "+v"(wn3),
                      "+v"(wn4), "+v"(wn5), "+v"(wn6), "+v"(wn7),
                      "+v"(wn8), "+v"(wn9), "+v"(wn10), "+v"(wn11),
                      "+v"(wn12), "+v"(wn13), "+v"(wn14), "+v"(wn15));

    float br = b_hh[l], bz = b_hh[64 + l], bn = b_hh[128 + l];

    float hp = h[v * H + l];
    hs[l] = hp;

    const float* xgv = xg + (size_t)v * CT * G3;
    int nck = (tcnt + CK - 1) >> 5;

    if (nck > 0) {
#pragma unroll
        for (int i = 0; i < 24; i++)
            __builtin_amdgcn_global_load_lds(
                (gvoid*)(xgv + i * 256 + l * 4), (lvoid*)&xb[0][i * 256], 16, 0, 0);
    }
    asm volatile("s_waitcnt vmcnt(0)" ::: "memory");

    const float LOG2E = 1.4426950408889634f;

    for (int ck = 0; ck < nck; ck++) {
        int buf = ck & 1;
        if (ck + 1 < nck) {
            const float* src = xgv + (size_t)(ck + 1) * CK * G3;
#pragma unroll
            for (int i = 0; i < 24; i++)
                __builtin_amdgcn_global_load_lds(
                    (gvoid*)(src + i * 256 + l * 4), (lvoid*)&xb[buf ^ 1][i * 256], 16, 0, 0);
        }
        int t1 = tcnt - ck * CK;
        if (t1 > CK) t1 = CK;

        for (int t = 0; t < t1; t++) {
            const float* xrow = &xb[buf][t * G3];

            vf4 hv0 = *(vf4*)&hs[0],  hv1 = *(vf4*)&hs[4];
            vf4 hv2 = *(vf4*)&hs[8],  hv3 = *(vf4*)&hs[12];
            vf4 hv4 = *(vf4*)&hs[16], hv5 = *(vf4*)&hs[20];
            vf4 hv6 = *(vf4*)&hs[24], hv7 = *(vf4*)&hs[28];
            vf4 hv8 = *(vf4*)&hs[32], hv9 = *(vf4*)&hs[36];
            vf4 hv10 = *(vf4*)&hs[40], hv11 = *(vf4*)&hs[44];
            vf4 hv12 = *(vf4*)&hs[48], hv13 = *(vf4*)&hs[52];
            vf4 hv14 = *(vf4*)&hs[56], hv15 = *(vf4*)&hs[60];

            float ar0 = 0.f, ar1 = 0.f, ar2 = 0.f, ar3 = 0.f;
            float az0 = 0.f, az1 = 0.f, az2 = 0.f, az3 = 0.f;
            float an0 = 0.f, an1 = 0.f, an2 = 0.f, an3 = 0.f;
            FMA4(ar0, wr0, hv0)   FMA4(ar0, wr1, hv1)   FMA4(ar0, wr2, hv2)   FMA4(ar0, wr3, hv3)
            FMA4(ar1, wr4, hv4)   FMA4(ar1, wr5, hv5)   FMA4(ar1, wr6, hv6)   FMA4(ar1, wr7, hv7)
            FMA4(ar2, wr8, hv8)   FMA4(ar2, wr9, hv9)   FMA4(ar2, wr10, hv10) FMA4(ar2, wr11, hv11)
            FMA4(ar3, wr12, hv12) FMA4(ar3, wr13, hv13) FMA4(ar3, wr14, hv14) FMA4(ar3, wr15, hv15)
            FMA4(az0, wz0, hv0)   FMA4(az0, wz1, hv1)   FMA4(az0, wz2, hv2)   FMA4(az0, wz3, hv3)
            FMA4(az1, wz4, hv4)   FMA4(az1, wz5, hv5)   FMA4(az1, wz6, hv6)   FMA4(az1, wz7, hv7)
            FMA4(az2, wz8, hv8)   FMA4(az2, wz9, hv9)   FMA4(az2, wz10, hv10) FMA4(az2, wz11, hv11)
            FMA4(az3, wz12, hv12) FMA4(az3, wz13, hv13) FMA4(az3, wz14, hv14) FMA4(az3, wz15, hv15)
            FMA4(an0, wn0, hv0)   FMA4(an0, wn1, hv1)   FMA4(an0, wn2, hv2)   FMA4(an0, wn3, hv3)
            FMA4(an1, wn4, hv4)   FMA4(an1, wn5, hv5)   FMA4(an1, wn6, hv6)   FMA4(an1, wn7, hv7)
            FMA4(an2, wn8, hv8)   FMA4(an2, wn9, hv9)   FMA4(an2, wn10, hv10) FMA4(an2, wn11, hv11)
            FMA4(an3, wn12, hv12) FMA4(an3, wn13, hv13) FMA4(an3, wn14, hv14) FMA4(an3, wn15, hv15)

            float ar = ((ar0 + ar1) + (ar2 + ar3)) + br;
            float az = ((az0 + az1) + (az2 + az3)) + bz;
            float an = ((an0 + an1) + (an2 + an3)) + bn;

            float r = __builtin_amdgcn_rcpf(1.f + __builtin_amdgcn_exp2f(-LOG2E * (ar + xrow[l])));
            float z = __builtin_amdgcn_rcpf(1.f + __builtin_amdgcn_exp2f(-LOG2E * (az + xrow[64 + l])));
            float targ = xrow[128 + l] + r * an;
            float e2 = __builtin_amdgcn_exp2f(-2.f * LOG2E * fabsf(targ));
            float tn = (1.f - e2) * __builtin_amdgcn_rcpf(1.f + e2);
            tn = __builtin_copysignf(tn, targ);
            hp = tn + z * (hp - tn);

            __builtin_amdgcn_wave_barrier();
            hs[l] = hp;
            __builtin_amdgcn_wave_barrier();
        }
        asm volatile("s_waitcnt vmcnt(0)" ::: "memory");
    }
    h[v * H + l] = hp;
}

// ---------------- K2F: fully-fused fallback (tiny workspace). Slow but correct.
__global__ __launch_bounds__(192) void k_rec_fused(
    const float* __restrict__ emb, const int* __restrict__ lengths,
    const float* __restrict__ W_ih, const float* __restrict__ b_ih,
    const float* __restrict__ W_hh, const float* __restrict__ b_hh,
    float* __restrict__ h) {
    int v = blockIdx.x;
    int th = threadIdx.x;
    int len = lengths[v];

    __shared__ __align__(16) float hs[H];
    __shared__ __align__(16) float es[ED];
    __shared__ float znbuf[128];
    __shared__ float xnbuf[64];

    float4 w4[16];
#pragma unroll
    for (int k4 = 0; k4 < 16; k4++)
        w4[k4] = *(const float4*)&W_hh[(size_t)th * H + k4 * 4];
    float bhh = b_hh[th];
    float bih = b_ih[th];
    if (th < H) hs[th] = 0.f;
    const float* ev = emb + (size_t)v * TMAX * ED;
    const float* wrow = W_ih + (size_t)th * ED;

    for (int t = 0; t < len; t++) {
        __syncthreads();
        for (int i = th; i < 128; i += 192)
            *(float4*)&es[i * 4] = *(const float4*)&ev[(size_t)t * ED + i * 4];
        __syncthreads();
        float xgt = bih;
        for (int k4 = 0; k4 < 128; k4++) {
            float4 wv = *(const float4*)&wrow[k4 * 4];
            float4 e4 = *(float4*)&es[k4 * 4];
            xgt += wv.x * e4.x + wv.y * e4.y + wv.z * e4.z + wv.w * e4.w;
        }
        float hg = bhh;
#pragma unroll
        for (int k4 = 0; k4 < 16; k4++) {
            float4 h4 = *(float4*)&hs[k4 * 4];
            hg += w4[k4].x * h4.x + w4[k4].y * h4.y + w4[k4].z * h4.z + w4[k4].w * h4.w;
        }
        if (th >= H && th < 128) znbuf[th - H] = hg + xgt;
        if (th >= 128) { znbuf[th - H] = hg; xnbuf[th - 128] = xgt; }
        __syncthreads();
        if (th < H) {
            float r = 1.f / (1.f + expf(-(hg + xgt)));
            float z = 1.f / (1.f + expf(-znbuf[th]));
            float n = tanhf(xnbuf[th] + r * znbuf[64 + th]);
            float hold = hs[th];
            hs[th] = (1.f - z) * n + z * hold;
        }
    }
    __syncthreads();
    if (th < H) h[v * H + th] = hs[th];
}

// ---------------- K3a: hid[o] = relu(b1[o] + W1[o,:] . concat)
__global__ __launch_bounds__(256) void k_mlp1(
    const float* __restrict__ h, const float* __restrict__ W1,
    const float* __restrict__ b1, float* __restrict__ hid) {
    int o = blockIdx.x, th = threadIdx.x;
    const float* w = W1 + (size_t)o * (V * H);
    float s = 0.f;
#pragma unroll
    for (int r = 0; r < 4; r++) {
        int i = (th + r * 256) * 4;
        float4 a = *(const float4*)&w[i];
        float4 b = *(const float4*)&h[i];
        s += a.x * b.x + a.y * b.y + a.z * b.z + a.w * b.w;
    }
    __shared__ float red[4];
    for (int off = 32; off; off >>= 1) s += __shfl_down(s, off);
    if ((th & 63) == 0) red[th >> 6] = s;
    __syncthreads();
    if (th == 0) {
        float tot = red[0] + red[1] + red[2] + red[3] + b1[o];
        hid[o] = tot > 0.f ? tot : 0.f;
    }
}

// ---------------- K3b: out = b2 + W2 . hid
__global__ void k_mlp2(const float* __restrict__ hid, const float* __restrict__ W2,
                       const float* __restrict__ b2, float* __restrict__ out) {
    int th = threadIdx.x;
    float s = hid[th] * W2[th];
    for (int off = 32; off; off >>= 1) s += __shfl_down(s, off);
    if (th == 0) out[0] = s + b2[0];
}

extern "C" void kernel_launch(void* const* d_in, const int* in_sizes, int n_in,
                              void* d_out, int out_size, void* d_ws, size_t ws_size,
                              hipStream_t stream) {
    const float* emb     = (const float*)d_in[0];
    const int*   lengths = (const int*)d_in[1];
    const float* W_ih    = (const float*)d_in[2];
    const float* W_hh    = (const float*)d_in[3];
    const float* b_ih    = (const float*)d_in[4];
    const float* b_hh    = (const float*)d_in[5];
    const float* W1      = (const float*)d_in[6];
    const float* b1      = (const float*)d_in[7];
    const float* W2      = (const float*)d_in[8];
    const float* b2      = (const float*)d_in[9];
    float* out = (float*)d_out;
    float* wsf = (float*)d_ws;

    const size_t tail = (size_t)V * H + V;  // h + hid (floats)
    int CT = 0;
    const int cts[5] = {2048, 1024, 512, 256, 128};
    for (int i = 0; i < 5; i++) {
        size_t need = ((size_t)V * cts[i] * G3 + tail) * sizeof(float);
        if (need <= ws_size) { CT = cts[i]; break; }
    }

    if (CT > 0) {
        float* xg  = wsf;
        float* hbf = wsf + (size_t)V * CT * G3;
        float* hid = hbf + (size_t)V * H;
        k_init<<<dim3((V * H + 255) / 256), dim3(256), 0, stream>>>(hbf);
        int nch = TMAX / CT;
        for (int c = 0; c < nch; c++) {
            k_gemm<<<dim3(CT / BT, V), dim3(256), 0, stream>>>(emb, lengths, W_ih, b_ih, xg, c, CT);
            k_rec<<<dim3(V), dim3(64), 0, stream>>>(xg, lengths, W_hh, b_hh, hbf, c, CT);
        }
        k_mlp1<<<dim3(V), dim3(256), 0, stream>>>(hbf, W1, b1, hid);
        k_mlp2<<<dim3(1), dim3(64), 0, stream>>>(hid, W2, b2, out);
    } else {
        float* hbf = wsf;
        float* hid = hbf + (size_t)V * H;
        k_rec_fused<<<dim3(V), dim3(192), 0, stream>>>(emb, lengths, W_ih, b_ih, W_hh, b_hh, hbf);
        k_mlp1<<<dim3(V), dim3(256), 0, stream>>>(hbf, W1, b1, hid);
        k_mlp2<<<dim3(1), dim3(64), 0, stream>>>(hid, W2, b2, out);
    }
}